// Round 17
// baseline (155.574 us; speedup 1.0000x reference)
//
#include <hip/hip_runtime.h>
#include <cmath>

namespace {
constexpr int NB  = 256;   // batch
constexpr int CI  = 64;    // in channels
constexpr int CO  = 64;    // out channels
constexpr int TT  = 64;    // time
constexpr int V   = 25;    // vertices
constexpr int REL = 8;     // rel channels
constexpr int TV  = TT * V;   // 1600
constexpr int CC  = 8;     // channels per block (Af + staging scope)
constexpr int THF = 32;    // t per staging half
constexpr int IP  = 28;    // inp row pad (16B-aligned rows)
constexpr int AP  = 28;    // Af row pad (16B-aligned rows)
}

typedef float f4 __attribute__((ext_vector_type(4)));

__device__ __forceinline__ float fast_tanh(float x) {
  float ax = fabsf(x);
  float e  = __expf(-2.f * ax);          // v_exp based
  float r  = (1.f - e) / (1.f + e);
  return copysignf(r, x);
}

// ---------------------------------------------------------------------------
// K1: per-n temporal reduction -> x1,x2 (REL*V each) into ws. (unchanged)
// ---------------------------------------------------------------------------
__global__ __launch_bounds__(1024) void k1_x12(
    const float* __restrict__ x,
    const float* __restrict__ w1, const float* __restrict__ b1,
    const float* __restrict__ w2, const float* __restrict__ b2,
    float* __restrict__ ws) {
  const int n = blockIdx.x;
  const int tid = threadIdx.x;
  __shared__ __align__(16) float xs[8][TV];
  __shared__ float xsum[CI][V];
  __shared__ float w12[2][REL][CI];

  for (int idx = tid; idx < 2 * REL * CI; idx += 1024) {
    int half = idx / (REL * CI), rem = idx % (REL * CI);
    w12[half][rem / CI][rem % CI] = half ? w2[rem] : w1[rem];
  }

  const float4* xb = reinterpret_cast<const float4*>(x + (size_t)n * (CI * TV));
  float4* xsv = reinterpret_cast<float4*>(&xs[0][0]);
  constexpr int V4G = 8 * TV / 4;  // 3200

  for (int g = 0; g < 8; ++g) {
    __syncthreads();
    for (int idx = tid; idx < V4G; idx += 1024)
      xsv[idx] = xb[g * V4G + idx];
    __syncthreads();
    if (tid < 8 * V) {
      int ch = tid / V, v = tid % V;
      float acc = 0.f;
      #pragma unroll
      for (int t = 0; t < TT; ++t) acc += xs[ch][t * V + v];
      xsum[g * 8 + ch][v] = acc;
    }
  }
  __syncthreads();

  if (tid < 2 * REL * V) {
    int half = tid / (REL * V), rem = tid % (REL * V);
    int r = rem / V, v = rem % V;
    float a = 0.f;
    #pragma unroll
    for (int i = 0; i < CI; ++i) a = fmaf(w12[half][r][i], xsum[i][v], a);
    ws[(size_t)n * (2 * REL * V) + tid] = a * (1.f / TT) + (half ? b2[r] : b1[r]);
  }
}

// ---------------------------------------------------------------------------
// K2 fused, t-halved staging (x read ONCE per block, Af built ONCE):
//   LDS = inp[8][32][28] (28672 B) + Afs[8][25][28] (22400 B) = 51072 B
//   -> 3 blocks/CU.
//   loop th=0,1: P1 stages all 8 channels for t-half th (200 threads x 64
//                float4 loads -- half of R16's VMEM issue and L2 bytes);
//                P2 consumes (256 thr, acc[4][7], t-rows tq+8*ti).
//   Plain stores; grid swizzle id=[n_hi5][cb3][n_lo3] -> 8 cb-blocks of an n
//   on one XCD. fast_tanh + minimal pad-zero kept.
// ---------------------------------------------------------------------------
__global__ __launch_bounds__(512, 4) void k2_fused(
    const float* __restrict__ x, const float* __restrict__ A,
    const float* __restrict__ w3, const float* __restrict__ b3,
    const float* __restrict__ wr, const float* __restrict__ br,
    const float* __restrict__ ws, float* __restrict__ out) {
  const int id  = blockIdx.x;
  const int n   = (id & 7) | ((id >> 3) & ~7);
  const int cb  = (id >> 3) & 7;
  const int c0  = cb * CC;
  const int tid = threadIdx.x;       // 0..511

  __shared__ __align__(16) float inp[CC * THF * IP];  // 28672 B
  __shared__ __align__(16) float Afs[CC * V * AP];    // 22400 B

  // ---- P0a: zero inp pad columns (v=25..27) for all 256 rows
  if (tid < CC * THF) {
    float* row = inp + tid * IP;
    row[25] = 0.f; row[26] = 0.f; row[27] = 0.f;
  }

  // ---- P0b: Af[cc][u][v] = A[u][v]+b3[c]+sum_r w3[c][r]*tanh(x1[r][u]-x2[r][v])
  //           pad columns (v>=25) = 0 (so f4 chunk 6 is safe)
  const float* x1n = ws + (size_t)n * (2 * REL * V);
  const float* x2n = x1n + REL * V;
  for (int idx = tid; idx < V * AP; idx += 512) {      // 700 tasks
    int u = idx / AP, v = idx % AP;
    if (v < V) {
      float t8[REL];
      #pragma unroll
      for (int r = 0; r < REL; ++r)
        t8[r] = fast_tanh(x1n[r * V + u] - x2n[r * V + v]);
      const float base = A[u * V + v];
      #pragma unroll
      for (int cc = 0; cc < CC; ++cc) {
        float acc = base + b3[c0 + cc];                // uniform -> s_load
        #pragma unroll
        for (int r = 0; r < REL; ++r)
          acc = fmaf(w3[(c0 + cc) * REL + r], t8[r], acc);  // uniform -> s_load
        Afs[(cc * V + u) * AP + v] = acc;
      }
    } else {
      #pragma unroll
      for (int cc = 0; cc < CC; ++cc)
        Afs[(cc * V + u) * AP + v] = 0.f;
    }
  }
  __syncthreads();

  for (int th = 0; th < 2; ++th) {
    // ---- P1: all 8 channels, t-half th. 200 threads own float4 tv-columns
    //          (tv in [th*800, th*800+800)). x[n] read exactly once per block.
    //          weights via uniform global reads -> s_load (SGPRs, not VGPRs).
    if (tid < THF * V / 4) {                           // 200 threads
      const float* xp = x + (size_t)n * (CI * TV) + th * (THF * V) + tid * 4;
      float acc[CC][4];
      #pragma unroll
      for (int cc = 0; cc < CC; ++cc) {
        float b = br[c0 + cc];                         // uniform -> s_load
        acc[cc][0] = b; acc[cc][1] = b; acc[cc][2] = b; acc[cc][3] = b;
      }
      #pragma unroll 8
      for (int i = 0; i < CI; ++i) {
        float4 xv = *reinterpret_cast<const float4*>(xp + (size_t)i * TV);
        float w8[CC];
        #pragma unroll
        for (int cc = 0; cc < CC; ++cc)
          w8[cc] = wr[(size_t)(c0 + cc) * CI + i];     // uniform -> s_load
        #pragma unroll
        for (int cc = 0; cc < CC; ++cc) {
          acc[cc][0] = fmaf(w8[cc], xv.x, acc[cc][0]);
          acc[cc][1] = fmaf(w8[cc], xv.y, acc[cc][1]);
          acc[cc][2] = fmaf(w8[cc], xv.z, acc[cc][2]);
          acc[cc][3] = fmaf(w8[cc], xv.w, acc[cc][3]);
        }
      }
      int tv0 = tid * 4;                               // within the half
      int t = tv0 / V, v = tv0 % V;                    // t in [0,32)
      #pragma unroll
      for (int k = 0; k < 4; ++k) {
        #pragma unroll
        for (int cc = 0; cc < CC; ++cc)
          inp[(cc * THF + t) * IP + v] = acc[cc][k];
        if (++v == V) { v = 0; ++t; }
      }
    }
    __syncthreads();

    // ---- P2 (tid < 256): thread = (cc, tq, uq). t-rows {tq+8*ti, ti=0..3}
    //      within the half; u-rows {6*uq .. 6*uq+6} (overlaps benign).
    //      acc[4][7]; per v-chunk: 4 inp f4 + 7 Af f4, consumed immediately.
    if (tid < 256) {
      const int cc = tid >> 5;          // 0..7
      const int tq = (tid >> 2) & 7;    // 0..7
      const int uq = tid & 3;           // 0..3
      const int u0 = uq * 6;

      float acc[4][7];
      #pragma unroll
      for (int a = 0; a < 4; ++a)
        #pragma unroll
        for (int b = 0; b < 7; ++b) acc[a][b] = 0.f;

      const float* ib = &inp[(cc * THF + tq) * IP];
      const float* ab = &Afs[(cc * V + u0) * AP];

      #pragma unroll
      for (int chk = 0; chk < 7; ++chk) {
        const f4 x0 = *reinterpret_cast<const f4*>(ib + 0 * 8 * IP + chk * 4);
        const f4 x1 = *reinterpret_cast<const f4*>(ib + 1 * 8 * IP + chk * 4);
        const f4 x2 = *reinterpret_cast<const f4*>(ib + 2 * 8 * IP + chk * 4);
        const f4 x3 = *reinterpret_cast<const f4*>(ib + 3 * 8 * IP + chk * 4);
        #pragma unroll
        for (int ku = 0; ku < 7; ++ku) {
          const f4 a = *reinterpret_cast<const f4*>(ab + ku * AP + chk * 4);
          acc[0][ku] = fmaf(a.w, x0.w, fmaf(a.z, x0.z, fmaf(a.y, x0.y, fmaf(a.x, x0.x, acc[0][ku]))));
          acc[1][ku] = fmaf(a.w, x1.w, fmaf(a.z, x1.z, fmaf(a.y, x1.y, fmaf(a.x, x1.x, acc[1][ku]))));
          acc[2][ku] = fmaf(a.w, x2.w, fmaf(a.z, x2.z, fmaf(a.y, x2.y, fmaf(a.x, x2.x, acc[2][ku]))));
          acc[3][ku] = fmaf(a.w, x3.w, fmaf(a.z, x3.z, fmaf(a.y, x3.y, fmaf(a.x, x3.x, acc[3][ku]))));
        }
      }

      float* ob = out + ((size_t)n * CO + (c0 + cc)) * (size_t)(TT * V)
                      + th * (THF * V);
      #pragma unroll
      for (int ti = 0; ti < 4; ++ti) {
        const int t = tq + 8 * ti;
        #pragma unroll
        for (int ku = 0; ku < 7; ++ku)
          ob[t * V + u0 + ku] = acc[ti][ku];
      }
    }
    if (th == 0) __syncthreads();   // P1(th=1) overwrites inp
  }
}

extern "C" void kernel_launch(void* const* d_in, const int* in_sizes, int n_in,
                              void* d_out, int out_size, void* d_ws, size_t ws_size,
                              hipStream_t stream) {
  (void)in_sizes; (void)n_in; (void)out_size; (void)ws_size;
  const float* x  = (const float*)d_in[0];
  const float* A  = (const float*)d_in[1];
  const float* w1 = (const float*)d_in[2];
  const float* b1 = (const float*)d_in[3];
  const float* w2 = (const float*)d_in[4];
  const float* b2 = (const float*)d_in[5];
  const float* w3 = (const float*)d_in[6];
  const float* b3 = (const float*)d_in[7];
  const float* wr = (const float*)d_in[8];
  const float* br = (const float*)d_in[9];
  float* out = (float*)d_out;
  float* ws  = (float*)d_ws;

  hipLaunchKernelGGL(k1_x12, dim3(NB), dim3(1024), 0, stream,
                     x, w1, b1, w2, b2, ws);
  hipLaunchKernelGGL(k2_fused, dim3(NB * CO / CC), dim3(512), 0, stream,
                     x, A, w3, b3, wr, br, ws, out);
}

// Round 18
// 139.336 us; speedup vs baseline: 1.1165x; 1.1165x over previous
//
#include <hip/hip_runtime.h>
#include <cmath>

namespace {
constexpr int NB  = 256;   // batch
constexpr int CI  = 64;    // in channels
constexpr int CO  = 64;    // out channels
constexpr int TT  = 64;    // time
constexpr int V   = 25;    // vertices
constexpr int REL = 8;     // rel channels
constexpr int TV  = TT * V;   // 1600
constexpr int CC  = 8;     // channels per block (Af scope)
constexpr int CH  = 4;     // channels per inp-staging half
constexpr int IP  = 28;    // inp row pad (16B-aligned rows)
constexpr int AP  = 28;    // Af row pad (16B-aligned rows)
constexpr int WS_X12 = NB * 2 * REL * V;   // 102400 floats: x1/x2
constexpr int WS_WRT = CI * CO;            // 4096 floats: wrT[i][c]
}

typedef float f4 __attribute__((ext_vector_type(4)));

__device__ __forceinline__ float fast_tanh(float x) {
  float ax = fabsf(x);
  float e  = __expf(-2.f * ax);          // v_exp based
  float r  = (1.f - e) / (1.f + e);
  return copysignf(r, x);
}

// ---------------------------------------------------------------------------
// K1: per-n temporal reduction -> x1,x2 into ws; block 0 also writes
// wrT[i][c] (transposed residual weights) after the x1/x2 region.
// ---------------------------------------------------------------------------
__global__ __launch_bounds__(1024) void k1_x12(
    const float* __restrict__ x,
    const float* __restrict__ w1, const float* __restrict__ b1,
    const float* __restrict__ w2, const float* __restrict__ b2,
    const float* __restrict__ wr, int write_wrt,
    float* __restrict__ ws) {
  const int n = blockIdx.x;
  const int tid = threadIdx.x;
  __shared__ __align__(16) float xs[8][TV];
  __shared__ float xsum[CI][V];
  __shared__ float w12[2][REL][CI];

  for (int idx = tid; idx < 2 * REL * CI; idx += 1024) {
    int half = idx / (REL * CI), rem = idx % (REL * CI);
    w12[half][rem / CI][rem % CI] = half ? w2[rem] : w1[rem];
  }

  // transposed residual weights for k2's P1 (contiguous s_load rows)
  if (n == 0 && write_wrt) {
    for (int idx = tid; idx < CI * CO; idx += 1024) {
      int i = idx >> 6, c = idx & 63;
      ws[WS_X12 + idx] = wr[(size_t)c * CI + i];     // wrT[i][c]
    }
  }

  const float4* xb = reinterpret_cast<const float4*>(x + (size_t)n * (CI * TV));
  float4* xsv = reinterpret_cast<float4*>(&xs[0][0]);
  constexpr int V4G = 8 * TV / 4;  // 3200

  for (int g = 0; g < 8; ++g) {
    __syncthreads();
    for (int idx = tid; idx < V4G; idx += 1024)
      xsv[idx] = xb[g * V4G + idx];
    __syncthreads();
    if (tid < 8 * V) {
      int ch = tid / V, v = tid % V;
      float acc = 0.f;
      #pragma unroll
      for (int t = 0; t < TT; ++t) acc += xs[ch][t * V + v];
      xsum[g * 8 + ch][v] = acc;
    }
  }
  __syncthreads();

  if (tid < 2 * REL * V) {
    int half = tid / (REL * V), rem = tid % (REL * V);
    int r = rem / V, v = rem % V;
    float a = 0.f;
    #pragma unroll
    for (int i = 0; i < CI; ++i) a = fmaf(w12[half][r][i], xsum[i][v], a);
    ws[(size_t)n * (2 * REL * V) + tid] = a * (1.f / TT) + (half ? b2[r] : b1[r]);
  }
}

// ---------------------------------------------------------------------------
// K2 fused == R16 (best: k2 131.8us) with ONE change: when WRT, P1 reads its
// 4 per-i weights as ONE contiguous s_load_dwordx4 from wrT[i][cbase..cbase+3]
// instead of 4 stride-64 s_load_dword (R16 issued 8/i; 512 scalar K$ ops per
// wave per half -> 64 merged vector s_loads).
//   LDS = inp[4][64][28] + Afs[8][25][28] = 51072 B -> 3 blocks/CU.
//   loop ch=0,1: P1 stages 4 channels (400 thr, float4 cols, unroll 8);
//                P2 consumes (256 thr, acc[4][7], t-rows tq+16*ti).
//   Plain stores; grid swizzle id=[n_hi5][cb3][n_lo3]; fast_tanh.
// ---------------------------------------------------------------------------
template <bool WRT>
__global__ __launch_bounds__(512, 4) void k2_fused(
    const float* __restrict__ x, const float* __restrict__ A,
    const float* __restrict__ w3, const float* __restrict__ b3,
    const float* __restrict__ wr, const float* __restrict__ br,
    const float* __restrict__ ws, float* __restrict__ out) {
  const int id  = blockIdx.x;
  const int n   = (id & 7) | ((id >> 3) & ~7);
  const int cb  = (id >> 3) & 7;
  const int c0  = cb * CC;
  const int tid = threadIdx.x;       // 0..511

  __shared__ __align__(16) float inp[CH * TT * IP];   // 28672 B
  __shared__ __align__(16) float Afs[CC * V * AP];    // 22400 B

  // ---- P0a: zero inp pad columns (v=25..27) for all 256 rows
  if (tid < CH * TT) {
    float* row = inp + tid * IP;
    row[25] = 0.f; row[26] = 0.f; row[27] = 0.f;
  }

  // ---- P0b: Af[cc][u][v] = A[u][v]+b3[c]+sum_r w3[c][r]*tanh(x1[r][u]-x2[r][v])
  const float* x1n = ws + (size_t)n * (2 * REL * V);
  const float* x2n = x1n + REL * V;
  for (int idx = tid; idx < V * AP; idx += 512) {      // 700 tasks
    int u = idx / AP, v = idx % AP;
    if (v < V) {
      float t8[REL];
      #pragma unroll
      for (int r = 0; r < REL; ++r)
        t8[r] = fast_tanh(x1n[r * V + u] - x2n[r * V + v]);
      const float base = A[u * V + v];
      #pragma unroll
      for (int cc = 0; cc < CC; ++cc) {
        float acc = base + b3[c0 + cc];                // uniform -> s_load
        #pragma unroll
        for (int r = 0; r < REL; ++r)
          acc = fmaf(w3[(c0 + cc) * REL + r], t8[r], acc);  // uniform -> s_load
        Afs[(cc * V + u) * AP + v] = acc;
      }
    } else {
      #pragma unroll
      for (int cc = 0; cc < CC; ++cc)
        Afs[(cc * V + u) * AP + v] = 0.f;
    }
  }
  __syncthreads();

  const float* wrt = ws + WS_X12;    // wrT[i][c] (valid iff WRT)

  for (int ch = 0; ch < 2; ++ch) {
    const int cbase = c0 + ch * CH;

    // ---- P1: inputs tile (all t, 4 channels) into LDS. 400 float4-columns.
    if (tid < TV / 4) {
      const float* xp = x + (size_t)n * (CI * TV) + tid * 4;
      float acc[CH][4];
      #pragma unroll
      for (int cc = 0; cc < CH; ++cc) {
        float b = br[cbase + cc];                      // uniform -> s_load
        acc[cc][0] = b; acc[cc][1] = b; acc[cc][2] = b; acc[cc][3] = b;
      }
      #pragma unroll 8
      for (int i = 0; i < CI; ++i) {
        float4 xv = *reinterpret_cast<const float4*>(xp + (size_t)i * TV);
        float w4[CH];
        if constexpr (WRT) {
          // contiguous 16B, wave-uniform -> one s_load_dwordx4
          const f4 wv = *reinterpret_cast<const f4*>(wrt + (size_t)i * CO + cbase);
          w4[0] = wv.x; w4[1] = wv.y; w4[2] = wv.z; w4[3] = wv.w;
        } else {
          #pragma unroll
          for (int cc = 0; cc < CH; ++cc)
            w4[cc] = wr[(size_t)(cbase + cc) * CI + i];
        }
        #pragma unroll
        for (int cc = 0; cc < CH; ++cc) {
          acc[cc][0] = fmaf(w4[cc], xv.x, acc[cc][0]);
          acc[cc][1] = fmaf(w4[cc], xv.y, acc[cc][1]);
          acc[cc][2] = fmaf(w4[cc], xv.z, acc[cc][2]);
          acc[cc][3] = fmaf(w4[cc], xv.w, acc[cc][3]);
        }
      }
      int tv0 = tid * 4;
      int t = tv0 / V, v = tv0 % V;
      #pragma unroll
      for (int k = 0; k < 4; ++k) {
        #pragma unroll
        for (int cc = 0; cc < CH; ++cc)
          inp[(cc * TT + t) * IP + v] = acc[cc][k];
        if (++v == V) { v = 0; ++t; }
      }
    }
    __syncthreads();

    // ---- P2 (tid < 256): thread = (ccl, tq, uq). t-rows {tq+16*ti};
    //      u-rows {6*uq .. 6*uq+6}. acc[4][7]; 11 f4 reads / 112 FMA per chk.
    if (tid < 256) {
      const int ccl = tid >> 6;         // 0..3
      const int tq  = (tid >> 2) & 15;  // 0..15
      const int uq  = tid & 3;          // 0..3
      const int u0  = uq * 6;

      float acc[4][7];
      #pragma unroll
      for (int a = 0; a < 4; ++a)
        #pragma unroll
        for (int b = 0; b < 7; ++b) acc[a][b] = 0.f;

      const float* ib = &inp[(ccl * TT + tq) * IP];
      const float* ab = &Afs[((ch * CH + ccl) * V + u0) * AP];

      #pragma unroll
      for (int chk = 0; chk < 7; ++chk) {
        const f4 x0 = *reinterpret_cast<const f4*>(ib + 0 * 16 * IP + chk * 4);
        const f4 x1 = *reinterpret_cast<const f4*>(ib + 1 * 16 * IP + chk * 4);
        const f4 x2 = *reinterpret_cast<const f4*>(ib + 2 * 16 * IP + chk * 4);
        const f4 x3 = *reinterpret_cast<const f4*>(ib + 3 * 16 * IP + chk * 4);
        #pragma unroll
        for (int ku = 0; ku < 7; ++ku) {
          const f4 a = *reinterpret_cast<const f4*>(ab + ku * AP + chk * 4);
          acc[0][ku] = fmaf(a.w, x0.w, fmaf(a.z, x0.z, fmaf(a.y, x0.y, fmaf(a.x, x0.x, acc[0][ku]))));
          acc[1][ku] = fmaf(a.w, x1.w, fmaf(a.z, x1.z, fmaf(a.y, x1.y, fmaf(a.x, x1.x, acc[1][ku]))));
          acc[2][ku] = fmaf(a.w, x2.w, fmaf(a.z, x2.z, fmaf(a.y, x2.y, fmaf(a.x, x2.x, acc[2][ku]))));
          acc[3][ku] = fmaf(a.w, x3.w, fmaf(a.z, x3.z, fmaf(a.y, x3.y, fmaf(a.x, x3.x, acc[3][ku]))));
        }
      }

      float* ob = out + ((size_t)n * CO + (cbase + ccl)) * (size_t)(TT * V);
      #pragma unroll
      for (int ti = 0; ti < 4; ++ti) {
        const int t = tq + 16 * ti;
        #pragma unroll
        for (int ku = 0; ku < 7; ++ku)
          ob[t * V + u0 + ku] = acc[ti][ku];
      }
    }
    if (ch == 0) __syncthreads();   // P1(ch=1) overwrites inp
  }
}

extern "C" void kernel_launch(void* const* d_in, const int* in_sizes, int n_in,
                              void* d_out, int out_size, void* d_ws, size_t ws_size,
                              hipStream_t stream) {
  (void)in_sizes; (void)n_in; (void)out_size;
  const float* x  = (const float*)d_in[0];
  const float* A  = (const float*)d_in[1];
  const float* w1 = (const float*)d_in[2];
  const float* b1 = (const float*)d_in[3];
  const float* w2 = (const float*)d_in[4];
  const float* b2 = (const float*)d_in[5];
  const float* w3 = (const float*)d_in[6];
  const float* b3 = (const float*)d_in[7];
  const float* wr = (const float*)d_in[8];
  const float* br = (const float*)d_in[9];
  float* out = (float*)d_out;
  float* ws  = (float*)d_ws;

  const bool wrt_ok = ws_size >= (size_t)(WS_X12 + WS_WRT) * sizeof(float);

  hipLaunchKernelGGL(k1_x12, dim3(NB), dim3(1024), 0, stream,
                     x, w1, b1, w2, b2, wr, (int)wrt_ok, ws);
  if (wrt_ok)
    hipLaunchKernelGGL(k2_fused<true>, dim3(NB * CO / CC), dim3(512), 0, stream,
                       x, A, w3, b3, wr, br, ws, out);
  else
    hipLaunchKernelGGL(k2_fused<false>, dim3(NB * CO / CC), dim3(512), 0, stream,
                       x, A, w3, b3, wr, br, ws, out);
}

// Round 21
// 138.290 us; speedup vs baseline: 1.1250x; 1.0076x over previous
//
#include <hip/hip_runtime.h>
#include <cmath>

namespace {
constexpr int NB  = 256;   // batch
constexpr int CI  = 64;    // in channels
constexpr int CO  = 64;    // out channels
constexpr int TT  = 64;    // time
constexpr int V   = 25;    // vertices
constexpr int REL = 8;     // rel channels
constexpr int TV  = TT * V;   // 1600
constexpr int CC  = 8;     // channels per block (Af scope)
constexpr int CH  = 4;     // channels per inp-staging half
constexpr int IP  = 28;    // inp row pad (16B-aligned rows)
constexpr int AP  = 28;    // Af row pad (16B-aligned rows)
}

typedef float f4 __attribute__((ext_vector_type(4)));

__device__ __forceinline__ float fast_tanh(float x) {
  float ax = fabsf(x);
  float e  = __expf(-2.f * ax);          // v_exp based
  float r  = (1.f - e) / (1.f + e);
  return copysignf(r, x);
}

// ---------------------------------------------------------------------------
// K1: per-n temporal reduction -> x1,x2 (REL*V each) into ws.
// ---------------------------------------------------------------------------
__global__ __launch_bounds__(1024) void k1_x12(
    const float* __restrict__ x,
    const float* __restrict__ w1, const float* __restrict__ b1,
    const float* __restrict__ w2, const float* __restrict__ b2,
    float* __restrict__ ws) {
  const int n = blockIdx.x;
  const int tid = threadIdx.x;
  __shared__ __align__(16) float xs[8][TV];
  __shared__ float xsum[CI][V];
  __shared__ float w12[2][REL][CI];

  for (int idx = tid; idx < 2 * REL * CI; idx += 1024) {
    int half = idx / (REL * CI), rem = idx % (REL * CI);
    w12[half][rem / CI][rem % CI] = half ? w2[rem] : w1[rem];
  }

  const float4* xb = reinterpret_cast<const float4*>(x + (size_t)n * (CI * TV));
  float4* xsv = reinterpret_cast<float4*>(&xs[0][0]);
  constexpr int V4G = 8 * TV / 4;  // 3200

  for (int g = 0; g < 8; ++g) {
    __syncthreads();
    for (int idx = tid; idx < V4G; idx += 1024)
      xsv[idx] = xb[g * V4G + idx];
    __syncthreads();
    if (tid < 8 * V) {
      int ch = tid / V, v = tid % V;
      float acc = 0.f;
      #pragma unroll
      for (int t = 0; t < TT; ++t) acc += xs[ch][t * V + v];
      xsum[g * 8 + ch][v] = acc;
    }
  }
  __syncthreads();

  if (tid < 2 * REL * V) {
    int half = tid / (REL * V), rem = tid % (REL * V);
    int r = rem / V, v = rem % V;
    float a = 0.f;
    #pragma unroll
    for (int i = 0; i < CI; ++i) a = fmaf(w12[half][r][i], xsum[i][v], a);
    ws[(size_t)n * (2 * REL * V) + tid] = a * (1.f / TT) + (half ? b2[r] : b1[r]);
  }
}

// ---------------------------------------------------------------------------
// K2 fused, cc-halved staging for 3 blocks/CU (best measured: R16, 138.4us):
//   LDS = inp[4][64][28] (28672 B) + Afs[8][25][28] (22400 B) = 51072 B.
//   Af built ONCE per block.
//   loop ch=0,1: P1 stages 4 channels' inputs (400 thr, float4 columns,
//                unroll 8); P2 consumes (256 thr, acc[4][7] -- the proven
//                11 LDS reads / 112 FMA density; t-rows tq+16*ti).
//   Plain stores (L2 merges the wave's full-line coverage; WRITE ~1.6x).
//   grid swizzle id=[n_hi5][cb3][n_lo3] -> 8 cb-blocks of an n on one XCD.
//   fast_tanh + minimal pad-zero; wr/br/w3/b3 via wave-uniform s_loads.
// ---------------------------------------------------------------------------
__global__ __launch_bounds__(512, 4) void k2_fused(
    const float* __restrict__ x, const float* __restrict__ A,
    const float* __restrict__ w3, const float* __restrict__ b3,
    const float* __restrict__ wr, const float* __restrict__ br,
    const float* __restrict__ ws, float* __restrict__ out) {
  const int id  = blockIdx.x;
  const int n   = (id & 7) | ((id >> 3) & ~7);
  const int cb  = (id >> 3) & 7;
  const int c0  = cb * CC;
  const int tid = threadIdx.x;       // 0..511

  __shared__ __align__(16) float inp[CH * TT * IP];   // 28672 B
  __shared__ __align__(16) float Afs[CC * V * AP];    // 22400 B

  // ---- P0a: zero inp pad columns (v=25..27) for all 256 rows
  if (tid < CH * TT) {
    float* row = inp + tid * IP;
    row[25] = 0.f; row[26] = 0.f; row[27] = 0.f;
  }

  // ---- P0b: Af[cc][u][v] = A[u][v]+b3[c]+sum_r w3[c][r]*tanh(x1[r][u]-x2[r][v])
  //           pad columns (v>=25) = 0 (so f4 chunk 6 is safe)
  const float* x1n = ws + (size_t)n * (2 * REL * V);
  const float* x2n = x1n + REL * V;
  for (int idx = tid; idx < V * AP; idx += 512) {      // 700 tasks
    int u = idx / AP, v = idx % AP;
    if (v < V) {
      float t8[REL];
      #pragma unroll
      for (int r = 0; r < REL; ++r)
        t8[r] = fast_tanh(x1n[r * V + u] - x2n[r * V + v]);
      const float base = A[u * V + v];
      #pragma unroll
      for (int cc = 0; cc < CC; ++cc) {
        float acc = base + b3[c0 + cc];                // uniform -> s_load
        #pragma unroll
        for (int r = 0; r < REL; ++r)
          acc = fmaf(w3[(c0 + cc) * REL + r], t8[r], acc);  // uniform -> s_load
        Afs[(cc * V + u) * AP + v] = acc;
      }
    } else {
      #pragma unroll
      for (int cc = 0; cc < CC; ++cc)
        Afs[(cc * V + u) * AP + v] = 0.f;
    }
  }
  __syncthreads();

  for (int ch = 0; ch < 2; ++ch) {
    const int cbase = c0 + ch * CH;

    // ---- P1: inputs tile (all t, 4 channels) into LDS. 400 float4-columns.
    //          weights via uniform global reads -> s_load.
    if (tid < TV / 4) {
      const float* xp = x + (size_t)n * (CI * TV) + tid * 4;
      float acc[CH][4];
      #pragma unroll
      for (int cc = 0; cc < CH; ++cc) {
        float b = br[cbase + cc];                      // uniform -> s_load
        acc[cc][0] = b; acc[cc][1] = b; acc[cc][2] = b; acc[cc][3] = b;
      }
      #pragma unroll 8
      for (int i = 0; i < CI; ++i) {
        float4 xv = *reinterpret_cast<const float4*>(xp + (size_t)i * TV);
        float w4[CH];
        #pragma unroll
        for (int cc = 0; cc < CH; ++cc)
          w4[cc] = wr[(size_t)(cbase + cc) * CI + i];  // uniform -> s_load
        #pragma unroll
        for (int cc = 0; cc < CH; ++cc) {
          acc[cc][0] = fmaf(w4[cc], xv.x, acc[cc][0]);
          acc[cc][1] = fmaf(w4[cc], xv.y, acc[cc][1]);
          acc[cc][2] = fmaf(w4[cc], xv.z, acc[cc][2]);
          acc[cc][3] = fmaf(w4[cc], xv.w, acc[cc][3]);
        }
      }
      int tv0 = tid * 4;
      int t = tv0 / V, v = tv0 % V;
      #pragma unroll
      for (int k = 0; k < 4; ++k) {
        #pragma unroll
        for (int cc = 0; cc < CH; ++cc)
          inp[(cc * TT + t) * IP + v] = acc[cc][k];
        if (++v == V) { v = 0; ++t; }
      }
    }
    __syncthreads();

    // ---- P2 (tid < 256): thread = (ccl, tq, uq). t-rows {tq+16*ti};
    //      u-rows {6*uq .. 6*uq+6} (overlaps benign). acc[4][7];
    //      per v-chunk: 4 inp f4 + 7 Af f4, consumed immediately.
    if (tid < 256) {
      const int ccl = tid >> 6;         // 0..3
      const int tq  = (tid >> 2) & 15;  // 0..15
      const int uq  = tid & 3;          // 0..3
      const int u0  = uq * 6;

      float acc[4][7];
      #pragma unroll
      for (int a = 0; a < 4; ++a)
        #pragma unroll
        for (int b = 0; b < 7; ++b) acc[a][b] = 0.f;

      const float* ib = &inp[(ccl * TT + tq) * IP];
      const float* ab = &Afs[((ch * CH + ccl) * V + u0) * AP];

      #pragma unroll
      for (int chk = 0; chk < 7; ++chk) {
        const f4 x0 = *reinterpret_cast<const f4*>(ib + 0 * 16 * IP + chk * 4);
        const f4 x1 = *reinterpret_cast<const f4*>(ib + 1 * 16 * IP + chk * 4);
        const f4 x2 = *reinterpret_cast<const f4*>(ib + 2 * 16 * IP + chk * 4);
        const f4 x3 = *reinterpret_cast<const f4*>(ib + 3 * 16 * IP + chk * 4);
        #pragma unroll
        for (int ku = 0; ku < 7; ++ku) {
          const f4 a = *reinterpret_cast<const f4*>(ab + ku * AP + chk * 4);
          acc[0][ku] = fmaf(a.w, x0.w, fmaf(a.z, x0.z, fmaf(a.y, x0.y, fmaf(a.x, x0.x, acc[0][ku]))));
          acc[1][ku] = fmaf(a.w, x1.w, fmaf(a.z, x1.z, fmaf(a.y, x1.y, fmaf(a.x, x1.x, acc[1][ku]))));
          acc[2][ku] = fmaf(a.w, x2.w, fmaf(a.z, x2.z, fmaf(a.y, x2.y, fmaf(a.x, x2.x, acc[2][ku]))));
          acc[3][ku] = fmaf(a.w, x3.w, fmaf(a.z, x3.z, fmaf(a.y, x3.y, fmaf(a.x, x3.x, acc[3][ku]))));
        }
      }

      float* ob = out + ((size_t)n * CO + (cbase + ccl)) * (size_t)(TT * V);
      #pragma unroll
      for (int ti = 0; ti < 4; ++ti) {
        const int t = tq + 16 * ti;
        #pragma unroll
        for (int ku = 0; ku < 7; ++ku)
          ob[t * V + u0 + ku] = acc[ti][ku];
      }
    }
    if (ch == 0) __syncthreads();   // P1(ch=1) overwrites inp
  }
}

extern "C" void kernel_launch(void* const* d_in, const int* in_sizes, int n_in,
                              void* d_out, int out_size, void* d_ws, size_t ws_size,
                              hipStream_t stream) {
  (void)in_sizes; (void)n_in; (void)out_size; (void)ws_size;
  const float* x  = (const float*)d_in[0];
  const float* A  = (const float*)d_in[1];
  const float* w1 = (const float*)d_in[2];
  const float* b1 = (const float*)d_in[3];
  const float* w2 = (const float*)d_in[4];
  const float* b2 = (const float*)d_in[5];
  const float* w3 = (const float*)d_in[6];
  const float* b3 = (const float*)d_in[7];
  const float* wr = (const float*)d_in[8];
  const float* br = (const float*)d_in[9];
  float* out = (float*)d_out;
  float* ws  = (float*)d_ws;

  hipLaunchKernelGGL(k1_x12, dim3(NB), dim3(1024), 0, stream,
                     x, w1, b1, w2, b2, ws);
  hipLaunchKernelGGL(k2_fused, dim3(NB * CO / CC), dim3(512), 0, stream,
                     x, A, w3, b3, wr, br, ws, out);
}

// Round 22
// 129.003 us; speedup vs baseline: 1.2060x; 1.0720x over previous
//
#include <hip/hip_runtime.h>
#include <cmath>

namespace {
constexpr int NB  = 256;   // batch
constexpr int CI  = 64;    // in channels
constexpr int CO  = 64;    // out channels
constexpr int TT  = 64;    // time
constexpr int V   = 25;    // vertices
constexpr int REL = 8;     // rel channels
constexpr int TV  = TT * V;   // 1600
constexpr int CC  = 4;     // channels per block (single pass)
constexpr int IP  = 28;    // inp row pad (16B-aligned rows)
constexpr int AP  = 28;    // Af row pad (16B-aligned rows)
}

typedef float f4 __attribute__((ext_vector_type(4)));

__device__ __forceinline__ float fast_tanh(float x) {
  float ax = fabsf(x);
  float e  = __expf(-2.f * ax);          // v_exp based
  float r  = (1.f - e) / (1.f + e);
  return copysignf(r, x);
}

// ---------------------------------------------------------------------------
// K1: per-n temporal reduction -> x1,x2 (REL*V each) into ws. (unchanged)
// ---------------------------------------------------------------------------
__global__ __launch_bounds__(1024) void k1_x12(
    const float* __restrict__ x,
    const float* __restrict__ w1, const float* __restrict__ b1,
    const float* __restrict__ w2, const float* __restrict__ b2,
    float* __restrict__ ws) {
  const int n = blockIdx.x;
  const int tid = threadIdx.x;
  __shared__ __align__(16) float xs[8][TV];
  __shared__ float xsum[CI][V];
  __shared__ float w12[2][REL][CI];

  for (int idx = tid; idx < 2 * REL * CI; idx += 1024) {
    int half = idx / (REL * CI), rem = idx % (REL * CI);
    w12[half][rem / CI][rem % CI] = half ? w2[rem] : w1[rem];
  }

  const float4* xb = reinterpret_cast<const float4*>(x + (size_t)n * (CI * TV));
  float4* xsv = reinterpret_cast<float4*>(&xs[0][0]);
  constexpr int V4G = 8 * TV / 4;  // 3200

  for (int g = 0; g < 8; ++g) {
    __syncthreads();
    for (int idx = tid; idx < V4G; idx += 1024)
      xsv[idx] = xb[g * V4G + idx];
    __syncthreads();
    if (tid < 8 * V) {
      int ch = tid / V, v = tid % V;
      float acc = 0.f;
      #pragma unroll
      for (int t = 0; t < TT; ++t) acc += xs[ch][t * V + v];
      xsum[g * 8 + ch][v] = acc;
    }
  }
  __syncthreads();

  if (tid < 2 * REL * V) {
    int half = tid / (REL * V), rem = tid % (REL * V);
    int r = rem / V, v = rem % V;
    float a = 0.f;
    #pragma unroll
    for (int i = 0; i < CI; ++i) a = fmaf(w12[half][r][i], xsum[i][v], a);
    ws[(size_t)n * (2 * REL * V) + tid] = a * (1.f / TT) + (half ? b2[r] : b1[r]);
  }
}

// ---------------------------------------------------------------------------
// K2 fused, CC=4 single-pass blocks for 4 blocks/CU:
//   LDS = inp[4][64][28] (28672 B) + Afs[4][25][28] (11200 B) = 39872 B
//   -> 4 blocks/CU (4x~40KB = 160KB), occupancy cap 100% (vs R16's 51KB/3blk).
//   4096 blocks of (n, 4-channel group); NO ch loop -> 2 barriers per block.
//   P1/P2 are byte-identical to R16's proven phases (400-thr float4 columns;
//   256-thr acc[4][7], 11 LDS reads / 112 FMA per chunk).
//   Total x L2 traffic unchanged: 16 block-reads of x[n] either way.
//   grid swizzle id=[n_hi5][cb4][n_lo3] -> 16 blocks of an n on one XCD.
//   fast_tanh + minimal pad-zero; wr/br/w3/b3 via wave-uniform s_loads.
// ---------------------------------------------------------------------------
__global__ __launch_bounds__(512, 4) void k2_fused(
    const float* __restrict__ x, const float* __restrict__ A,
    const float* __restrict__ w3, const float* __restrict__ b3,
    const float* __restrict__ wr, const float* __restrict__ br,
    const float* __restrict__ ws, float* __restrict__ out) {
  const int id  = blockIdx.x;
  const int n   = (id & 7) | ((id >> 7) << 3);
  const int cb  = (id >> 3) & 15;
  const int c0  = cb * CC;
  const int tid = threadIdx.x;       // 0..511

  __shared__ __align__(16) float inp[CC * TT * IP];   // 28672 B
  __shared__ __align__(16) float Afs[CC * V * AP];    // 11200 B

  // ---- P0a: zero inp pad columns (v=25..27) for all 256 rows
  if (tid < CC * TT) {
    float* row = inp + tid * IP;
    row[25] = 0.f; row[26] = 0.f; row[27] = 0.f;
  }

  // ---- P0b: Af[cc][u][v] = A[u][v]+b3[c]+sum_r w3[c][r]*tanh(x1[r][u]-x2[r][v])
  //           pad columns (v>=25) = 0 (so f4 chunk 6 is safe)
  const float* x1n = ws + (size_t)n * (2 * REL * V);
  const float* x2n = x1n + REL * V;
  for (int idx = tid; idx < V * AP; idx += 512) {      // 700 tasks
    int u = idx / AP, v = idx % AP;
    if (v < V) {
      float t8[REL];
      #pragma unroll
      for (int r = 0; r < REL; ++r)
        t8[r] = fast_tanh(x1n[r * V + u] - x2n[r * V + v]);
      const float base = A[u * V + v];
      #pragma unroll
      for (int cc = 0; cc < CC; ++cc) {
        float acc = base + b3[c0 + cc];                // uniform -> s_load
        #pragma unroll
        for (int r = 0; r < REL; ++r)
          acc = fmaf(w3[(c0 + cc) * REL + r], t8[r], acc);  // uniform -> s_load
        Afs[(cc * V + u) * AP + v] = acc;
      }
    } else {
      #pragma unroll
      for (int cc = 0; cc < CC; ++cc)
        Afs[(cc * V + u) * AP + v] = 0.f;
    }
  }
  __syncthreads();

  // ---- P1: inputs tile (all t, 4 channels) into LDS. 400 float4-columns.
  //          weights via uniform global reads -> s_load.
  if (tid < TV / 4) {
    const float* xp = x + (size_t)n * (CI * TV) + tid * 4;
    float acc[CC][4];
    #pragma unroll
    for (int cc = 0; cc < CC; ++cc) {
      float b = br[c0 + cc];                           // uniform -> s_load
      acc[cc][0] = b; acc[cc][1] = b; acc[cc][2] = b; acc[cc][3] = b;
    }
    #pragma unroll 8
    for (int i = 0; i < CI; ++i) {
      float4 xv = *reinterpret_cast<const float4*>(xp + (size_t)i * TV);
      float w4[CC];
      #pragma unroll
      for (int cc = 0; cc < CC; ++cc)
        w4[cc] = wr[(size_t)(c0 + cc) * CI + i];       // uniform -> s_load
      #pragma unroll
      for (int cc = 0; cc < CC; ++cc) {
        acc[cc][0] = fmaf(w4[cc], xv.x, acc[cc][0]);
        acc[cc][1] = fmaf(w4[cc], xv.y, acc[cc][1]);
        acc[cc][2] = fmaf(w4[cc], xv.z, acc[cc][2]);
        acc[cc][3] = fmaf(w4[cc], xv.w, acc[cc][3]);
      }
    }
    int tv0 = tid * 4;
    int t = tv0 / V, v = tv0 % V;
    #pragma unroll
    for (int k = 0; k < 4; ++k) {
      #pragma unroll
      for (int cc = 0; cc < CC; ++cc)
        inp[(cc * TT + t) * IP + v] = acc[cc][k];
      if (++v == V) { v = 0; ++t; }
    }
  }
  __syncthreads();

  // ---- P2 (tid < 256): thread = (ccl, tq, uq). t-rows {tq+16*ti, ti=0..3};
  //      u-rows {6*uq .. 6*uq+6} (overlaps benign). acc[4][7];
  //      per v-chunk: 4 inp f4 + 7 Af f4, consumed immediately.
  if (tid < 256) {
    const int ccl = tid >> 6;         // 0..3
    const int tq  = (tid >> 2) & 15;  // 0..15
    const int uq  = tid & 3;          // 0..3
    const int u0  = uq * 6;

    float acc[4][7];
    #pragma unroll
    for (int a = 0; a < 4; ++a)
      #pragma unroll
      for (int b = 0; b < 7; ++b) acc[a][b] = 0.f;

    const float* ib = &inp[(ccl * TT + tq) * IP];
    const float* ab = &Afs[(ccl * V + u0) * AP];

    #pragma unroll
    for (int chk = 0; chk < 7; ++chk) {
      const f4 x0 = *reinterpret_cast<const f4*>(ib + 0 * 16 * IP + chk * 4);
      const f4 x1 = *reinterpret_cast<const f4*>(ib + 1 * 16 * IP + chk * 4);
      const f4 x2 = *reinterpret_cast<const f4*>(ib + 2 * 16 * IP + chk * 4);
      const f4 x3 = *reinterpret_cast<const f4*>(ib + 3 * 16 * IP + chk * 4);
      #pragma unroll
      for (int ku = 0; ku < 7; ++ku) {
        const f4 a = *reinterpret_cast<const f4*>(ab + ku * AP + chk * 4);
        acc[0][ku] = fmaf(a.w, x0.w, fmaf(a.z, x0.z, fmaf(a.y, x0.y, fmaf(a.x, x0.x, acc[0][ku]))));
        acc[1][ku] = fmaf(a.w, x1.w, fmaf(a.z, x1.z, fmaf(a.y, x1.y, fmaf(a.x, x1.x, acc[1][ku]))));
        acc[2][ku] = fmaf(a.w, x2.w, fmaf(a.z, x2.z, fmaf(a.y, x2.y, fmaf(a.x, x2.x, acc[2][ku]))));
        acc[3][ku] = fmaf(a.w, x3.w, fmaf(a.z, x3.z, fmaf(a.y, x3.y, fmaf(a.x, x3.x, acc[3][ku]))));
      }
    }

    float* ob = out + ((size_t)n * CO + (c0 + ccl)) * (size_t)(TT * V);
    #pragma unroll
    for (int ti = 0; ti < 4; ++ti) {
      const int t = tq + 16 * ti;
      #pragma unroll
      for (int ku = 0; ku < 7; ++ku)
        ob[t * V + u0 + ku] = acc[ti][ku];
    }
  }
}

extern "C" void kernel_launch(void* const* d_in, const int* in_sizes, int n_in,
                              void* d_out, int out_size, void* d_ws, size_t ws_size,
                              hipStream_t stream) {
  (void)in_sizes; (void)n_in; (void)out_size; (void)ws_size;
  const float* x  = (const float*)d_in[0];
  const float* A  = (const float*)d_in[1];
  const float* w1 = (const float*)d_in[2];
  const float* b1 = (const float*)d_in[3];
  const float* w2 = (const float*)d_in[4];
  const float* b2 = (const float*)d_in[5];
  const float* w3 = (const float*)d_in[6];
  const float* b3 = (const float*)d_in[7];
  const float* wr = (const float*)d_in[8];
  const float* br = (const float*)d_in[9];
  float* out = (float*)d_out;
  float* ws  = (float*)d_ws;

  hipLaunchKernelGGL(k1_x12, dim3(NB), dim3(1024), 0, stream,
                     x, w1, b1, w2, b2, ws);
  hipLaunchKernelGGL(k2_fused, dim3(NB * CO / CC), dim3(512), 0, stream,
                     x, A, w3, b3, wr, br, ws, out);
}

// Round 23
// 124.384 us; speedup vs baseline: 1.2508x; 1.0371x over previous
//
#include <hip/hip_runtime.h>
#include <cmath>

namespace {
constexpr int NB  = 256;   // batch
constexpr int CI  = 64;    // in channels
constexpr int CO  = 64;    // out channels
constexpr int TT  = 64;    // time
constexpr int V   = 25;    // vertices
constexpr int REL = 8;     // rel channels
constexpr int TV  = TT * V;   // 1600
constexpr int CC  = 4;     // channels per block (single pass)
constexpr int IP  = 28;    // inp row pad (16B-aligned rows)
constexpr int AP  = 28;    // Af row pad (16B-aligned rows)
}

typedef float f4 __attribute__((ext_vector_type(4)));

__device__ __forceinline__ float fast_tanh(float x) {
  float ax = fabsf(x);
  float e  = __expf(-2.f * ax);          // v_exp based
  float r  = (1.f - e) / (1.f + e);
  return copysignf(r, x);
}

// ---------------------------------------------------------------------------
// K1: per-n temporal reduction -> x1,x2 (REL*V each) into ws. (unchanged)
// ---------------------------------------------------------------------------
__global__ __launch_bounds__(1024) void k1_x12(
    const float* __restrict__ x,
    const float* __restrict__ w1, const float* __restrict__ b1,
    const float* __restrict__ w2, const float* __restrict__ b2,
    float* __restrict__ ws) {
  const int n = blockIdx.x;
  const int tid = threadIdx.x;
  __shared__ __align__(16) float xs[8][TV];
  __shared__ float xsum[CI][V];
  __shared__ float w12[2][REL][CI];

  for (int idx = tid; idx < 2 * REL * CI; idx += 1024) {
    int half = idx / (REL * CI), rem = idx % (REL * CI);
    w12[half][rem / CI][rem % CI] = half ? w2[rem] : w1[rem];
  }

  const float4* xb = reinterpret_cast<const float4*>(x + (size_t)n * (CI * TV));
  float4* xsv = reinterpret_cast<float4*>(&xs[0][0]);
  constexpr int V4G = 8 * TV / 4;  // 3200

  for (int g = 0; g < 8; ++g) {
    __syncthreads();
    for (int idx = tid; idx < V4G; idx += 1024)
      xsv[idx] = xb[g * V4G + idx];
    __syncthreads();
    if (tid < 8 * V) {
      int ch = tid / V, v = tid % V;
      float acc = 0.f;
      #pragma unroll
      for (int t = 0; t < TT; ++t) acc += xs[ch][t * V + v];
      xsum[g * 8 + ch][v] = acc;
    }
  }
  __syncthreads();

  if (tid < 2 * REL * V) {
    int half = tid / (REL * V), rem = tid % (REL * V);
    int r = rem / V, v = rem % V;
    float a = 0.f;
    #pragma unroll
    for (int i = 0; i < CI; ++i) a = fmaf(w12[half][r][i], xsum[i][v], a);
    ws[(size_t)n * (2 * REL * V) + tid] = a * (1.f / TT) + (half ? b2[r] : b1[r]);
  }
}

// ---------------------------------------------------------------------------
// K2 fused, CC=4 single-pass blocks (R22 frame, 4 blocks/CU) with P2 on ALL
// 512 threads:
//   P2 remap: ccl(4) x tq(32) x uq(4) = 512; acc[2][7]; t-rows {tq, tq+32}.
//   Per-wave VALU halves (392 FMA); DS 63 b128 reads/thread; pipes balanced.
//   Af reads/wave: 4 distinct addrs, 672B apart -> banks {0-3,8-11,16-19,
//   24-27}, conflict-free. inp reads worst 2-way (free).
//   Everything else R22-verbatim: LDS 39872 B -> 4 blocks/CU; 4096 blocks;
//   grid swizzle id=[n_hi5][cb4][n_lo3]; fast_tanh; plain stores; s_load
//   weights.
// ---------------------------------------------------------------------------
__global__ __launch_bounds__(512, 4) void k2_fused(
    const float* __restrict__ x, const float* __restrict__ A,
    const float* __restrict__ w3, const float* __restrict__ b3,
    const float* __restrict__ wr, const float* __restrict__ br,
    const float* __restrict__ ws, float* __restrict__ out) {
  const int id  = blockIdx.x;
  const int n   = (id & 7) | ((id >> 7) << 3);
  const int cb  = (id >> 3) & 15;
  const int c0  = cb * CC;
  const int tid = threadIdx.x;       // 0..511

  __shared__ __align__(16) float inp[CC * TT * IP];   // 28672 B
  __shared__ __align__(16) float Afs[CC * V * AP];    // 11200 B

  // ---- P0a: zero inp pad columns (v=25..27) for all 256 rows
  if (tid < CC * TT) {
    float* row = inp + tid * IP;
    row[25] = 0.f; row[26] = 0.f; row[27] = 0.f;
  }

  // ---- P0b: Af[cc][u][v] = A[u][v]+b3[c]+sum_r w3[c][r]*tanh(x1[r][u]-x2[r][v])
  //           pad columns (v>=25) = 0 (so f4 chunk 6 is safe)
  const float* x1n = ws + (size_t)n * (2 * REL * V);
  const float* x2n = x1n + REL * V;
  for (int idx = tid; idx < V * AP; idx += 512) {      // 700 tasks
    int u = idx / AP, v = idx % AP;
    if (v < V) {
      float t8[REL];
      #pragma unroll
      for (int r = 0; r < REL; ++r)
        t8[r] = fast_tanh(x1n[r * V + u] - x2n[r * V + v]);
      const float base = A[u * V + v];
      #pragma unroll
      for (int cc = 0; cc < CC; ++cc) {
        float acc = base + b3[c0 + cc];                // uniform -> s_load
        #pragma unroll
        for (int r = 0; r < REL; ++r)
          acc = fmaf(w3[(c0 + cc) * REL + r], t8[r], acc);  // uniform -> s_load
        Afs[(cc * V + u) * AP + v] = acc;
      }
    } else {
      #pragma unroll
      for (int cc = 0; cc < CC; ++cc)
        Afs[(cc * V + u) * AP + v] = 0.f;
    }
  }
  __syncthreads();

  // ---- P1: inputs tile (all t, 4 channels) into LDS. 400 float4-columns.
  //          weights via uniform global reads -> s_load.
  if (tid < TV / 4) {
    const float* xp = x + (size_t)n * (CI * TV) + tid * 4;
    float acc[CC][4];
    #pragma unroll
    for (int cc = 0; cc < CC; ++cc) {
      float b = br[c0 + cc];                           // uniform -> s_load
      acc[cc][0] = b; acc[cc][1] = b; acc[cc][2] = b; acc[cc][3] = b;
    }
    #pragma unroll 8
    for (int i = 0; i < CI; ++i) {
      float4 xv = *reinterpret_cast<const float4*>(xp + (size_t)i * TV);
      float w4[CC];
      #pragma unroll
      for (int cc = 0; cc < CC; ++cc)
        w4[cc] = wr[(size_t)(c0 + cc) * CI + i];       // uniform -> s_load
      #pragma unroll
      for (int cc = 0; cc < CC; ++cc) {
        acc[cc][0] = fmaf(w4[cc], xv.x, acc[cc][0]);
        acc[cc][1] = fmaf(w4[cc], xv.y, acc[cc][1]);
        acc[cc][2] = fmaf(w4[cc], xv.z, acc[cc][2]);
        acc[cc][3] = fmaf(w4[cc], xv.w, acc[cc][3]);
      }
    }
    int tv0 = tid * 4;
    int t = tv0 / V, v = tv0 % V;
    #pragma unroll
    for (int k = 0; k < 4; ++k) {
      #pragma unroll
      for (int cc = 0; cc < CC; ++cc)
        inp[(cc * TT + t) * IP + v] = acc[cc][k];
      if (++v == V) { v = 0; ++t; }
    }
  }
  __syncthreads();

  // ---- P2 (ALL 512 threads): thread = (ccl, tq, uq). t-rows {tq, tq+32};
  //      u-rows {6*uq .. 6*uq+6} (overlaps benign). acc[2][7];
  //      per v-chunk: 2 inp f4 + 7 Af f4, consumed immediately.
  {
    const int ccl = tid >> 7;         // 0..3
    const int tq  = (tid >> 2) & 31;  // 0..31
    const int uq  = tid & 3;          // 0..3
    const int u0  = uq * 6;

    float acc[2][7];
    #pragma unroll
    for (int a = 0; a < 2; ++a)
      #pragma unroll
      for (int b = 0; b < 7; ++b) acc[a][b] = 0.f;

    const float* ib = &inp[(ccl * TT + tq) * IP];
    const float* ab = &Afs[(ccl * V + u0) * AP];

    #pragma unroll
    for (int chk = 0; chk < 7; ++chk) {
      const f4 x0 = *reinterpret_cast<const f4*>(ib + chk * 4);
      const f4 x1 = *reinterpret_cast<const f4*>(ib + 32 * IP + chk * 4);
      #pragma unroll
      for (int ku = 0; ku < 7; ++ku) {
        const f4 a = *reinterpret_cast<const f4*>(ab + ku * AP + chk * 4);
        acc[0][ku] = fmaf(a.w, x0.w, fmaf(a.z, x0.z, fmaf(a.y, x0.y, fmaf(a.x, x0.x, acc[0][ku]))));
        acc[1][ku] = fmaf(a.w, x1.w, fmaf(a.z, x1.z, fmaf(a.y, x1.y, fmaf(a.x, x1.x, acc[1][ku]))));
      }
    }

    float* ob = out + ((size_t)n * CO + (c0 + ccl)) * (size_t)(TT * V);
    #pragma unroll
    for (int ti = 0; ti < 2; ++ti) {
      const int t = tq + 32 * ti;
      #pragma unroll
      for (int ku = 0; ku < 7; ++ku)
        ob[t * V + u0 + ku] = acc[ti][ku];
    }
  }
}

extern "C" void kernel_launch(void* const* d_in, const int* in_sizes, int n_in,
                              void* d_out, int out_size, void* d_ws, size_t ws_size,
                              hipStream_t stream) {
  (void)in_sizes; (void)n_in; (void)out_size; (void)ws_size;
  const float* x  = (const float*)d_in[0];
  const float* A  = (const float*)d_in[1];
  const float* w1 = (const float*)d_in[2];
  const float* b1 = (const float*)d_in[3];
  const float* w2 = (const float*)d_in[4];
  const float* b2 = (const float*)d_in[5];
  const float* w3 = (const float*)d_in[6];
  const float* b3 = (const float*)d_in[7];
  const float* wr = (const float*)d_in[8];
  const float* br = (const float*)d_in[9];
  float* out = (float*)d_out;
  float* ws  = (float*)d_ws;

  hipLaunchKernelGGL(k1_x12, dim3(NB), dim3(1024), 0, stream,
                     x, w1, b1, w2, b2, ws);
  hipLaunchKernelGGL(k2_fused, dim3(NB * CO / CC), dim3(512), 0, stream,
                     x, A, w3, b3, wr, br, ws, out);
}